// Round 8
// baseline (315.173 us; speedup 1.0000x reference)
//
#include <hip/hip_runtime.h>
#include <math.h>

#define N_NODES 50000
#define N_EDGES 500000
#define D_IN 512
#define D_H  512
#define D_OUT 256
#define NB 196  // ceil(N_NODES/256)

typedef __attribute__((ext_vector_type(8))) short bf16x8;
typedef __attribute__((ext_vector_type(8))) unsigned short ushort8;
typedef __attribute__((ext_vector_type(4))) float f32x4;

__device__ __forceinline__ float b2f(unsigned short u) {
    union { unsigned int i; float f; } v; v.i = ((unsigned int)u) << 16; return v.f;
}
__device__ __forceinline__ unsigned short f2b(float f) {
    unsigned int x = __float_as_uint(f);
    unsigned int r = (x + 0x7fffu + ((x >> 16) & 1u)) >> 16;  // RNE
    return (unsigned short)r;
}

// ---------------- weight transpose: W [K][N] fp32 -> Wt [N][K] bf16 ----------------

__global__ void k_wt(const float* __restrict__ W, unsigned short* __restrict__ Wt,
                     int K, int N) {
    __shared__ float t[32][33];
    const int bk = blockIdx.x * 32, bn = blockIdx.y * 32;
    const int tx = threadIdx.x, ty = threadIdx.y;  // (32,8)
    for (int i = ty; i < 32; i += 8) t[i][tx] = W[(size_t)(bk + i) * N + bn + tx];
    __syncthreads();
    for (int i = ty; i < 32; i += 8)
        Wt[(size_t)(bn + i) * K + bk + tx] = f2b(t[tx][i]);
}

// ---------------- degree / CSR build ----------------

__global__ __launch_bounds__(256) void k_zero(int* __restrict__ p, int n) {
    int i = blockIdx.x * 256 + threadIdx.x;
    if (i < n) p[i] = 0;
}

__global__ __launch_bounds__(256) void k_indeg(const int* __restrict__ dst,
                                               int* __restrict__ indeg) {
    int i = blockIdx.x * 256 + threadIdx.x;
    if (i < N_EDGES) atomicAdd(&indeg[dst[i]], 1);
}

__global__ __launch_bounds__(256) void k_partials(const int* __restrict__ indeg,
                                                  int* __restrict__ bsum) {
    __shared__ int wsum[4];
    const int tid = threadIdx.x, lane = tid & 63, w = tid >> 6;
    const int i = blockIdx.x * 256 + tid;
    int v = (i < N_NODES) ? indeg[i] : 0;
#pragma unroll
    for (int o = 32; o > 0; o >>= 1) v += __shfl_down(v, o, 64);
    if (lane == 0) wsum[w] = v;
    __syncthreads();
    if (tid == 0) bsum[blockIdx.x] = wsum[0] + wsum[1] + wsum[2] + wsum[3];
}

__global__ __launch_bounds__(256) void k_scanb(const int* __restrict__ bsum,
                                               int* __restrict__ boff) {
    __shared__ int wsum[4];
    const int tid = threadIdx.x, lane = tid & 63, w = tid >> 6;
    const int v = (tid < NB) ? bsum[tid] : 0;
    int s = v;
#pragma unroll
    for (int o = 1; o < 64; o <<= 1) {
        int t = __shfl_up(s, o, 64);
        if (lane >= o) s += t;
    }
    if (lane == 63) wsum[w] = s;
    __syncthreads();
    int add = 0;
    for (int k = 0; k < w; ++k) add += wsum[k];
    if (tid < NB) boff[tid] = add + s - v;
}

__global__ __launch_bounds__(256) void k_finalize(const int* __restrict__ indeg,
                                                  const int* __restrict__ boff,
                                                  int* __restrict__ row_start,
                                                  int* __restrict__ cursor,
                                                  float* __restrict__ dinv) {
    __shared__ int wsum[4];
    const int tid = threadIdx.x, lane = tid & 63, w = tid >> 6;
    const int i = blockIdx.x * 256 + tid;
    const int v = (i < N_NODES) ? indeg[i] : 0;
    int s = v;
#pragma unroll
    for (int o = 1; o < 64; o <<= 1) {
        int t = __shfl_up(s, o, 64);
        if (lane >= o) s += t;
    }
    if (lane == 63) wsum[w] = s;
    __syncthreads();
    int add = boff[blockIdx.x];
    for (int k = 0; k < w; ++k) add += wsum[k];
    if (i < N_NODES) {
        const int excl = add + s - v;
        row_start[i] = excl;
        cursor[i] = excl;
        dinv[i] = rsqrtf((float)(1 + v));
    }
    if (i == N_NODES) row_start[N_NODES] = N_EDGES;
}

__global__ __launch_bounds__(256) void k_bucket(const int* __restrict__ src,
                                                const int* __restrict__ dst,
                                                int* __restrict__ cursor,
                                                int* __restrict__ csr_src) {
    int e = blockIdx.x * 256 + threadIdx.x;
    if (e >= N_EDGES) return;
    int pos = atomicAdd(&cursor[dst[e]], 1);
    csr_src[pos] = src[e];
}

// ---------------- 128x128 bf16 MFMA GEMM, BK=64, dbuf, swizzled LDS ----------------
// C[M,N] = A[M,K] @ Bt[N,K]^T, fp32 accum -> bf16 C.
// 256 threads = 4 waves 2x2, per-wave 64x64 (4x4 frags of 16x16x32, 2 k-halves).
// nt = K/64 = 8 barrier steps (halved vs BK=32) — tests per-step fixed-cost theory.
// LDS layout per operand: [128 rows][8 chunks of 8 bf16], chunk stored at
// (cpos ^ (row&7)) — involution applied on gload SOURCE and ds_read side.

__device__ __forceinline__ void gload16(const void* g, void* l) {
    __builtin_amdgcn_global_load_lds(
        (const __attribute__((address_space(1))) unsigned int*)g,
        (__attribute__((address_space(3))) unsigned int*)l, 16, 0, 0);
}

template <bool A32>
__global__ __launch_bounds__(256, 2) void k_gemm(const void* __restrict__ Av,
                                                 const unsigned short* __restrict__ Bt,
                                                 unsigned short* __restrict__ C,
                                                 int M, int N, int K) {
    __shared__ __align__(16) short As[2][128 * 64];  // 16 KB x2
    __shared__ __align__(16) short Bs[2][128 * 64];  // 16 KB x2

    const int tid = threadIdx.x;
    const int wid = tid >> 6;
    const int lane = tid & 63;
    const int wr = wid >> 1, wc = wid & 1;
    const int brow = blockIdx.y * 128;
    const int bcol = blockIdx.x * 128;
    const int lhi = lane >> 4, llo = lane & 15;

    f32x4 acc[4][4];
#pragma unroll
    for (int i = 0; i < 4; ++i)
#pragma unroll
        for (int j = 0; j < 4; ++j) acc[i][j] = (f32x4){0.f, 0.f, 0.f, 0.f};

    const float* Af = (const float*)Av;
    const unsigned short* Ab = (const unsigned short*)Av;

    // slot geometry: s = g*256 + tid (g<4); row = s>>3; cpos = s&7; sc = cpos^(row&7)
    float4 ar[4][2];  // A32 reg staging (static-indexed)

#define STAGE_B(buf, kt)                                                        \
    {                                                                           \
        _Pragma("unroll") for (int g = 0; g < 4; ++g) {                         \
            const int s = g * 256 + tid;                                        \
            const int row = s >> 3;                                             \
            const int sc = (s & 7) ^ (row & 7);                                 \
            gload16(Bt + (size_t)(bcol + row) * K + (kt) + sc * 8,              \
                    &Bs[buf][(g * 256 + wid * 64) * 8]);                        \
        }                                                                       \
    }
#define STAGE_A16(buf, kt)                                                      \
    {                                                                           \
        _Pragma("unroll") for (int g = 0; g < 4; ++g) {                         \
            const int s = g * 256 + tid;                                        \
            const int row = s >> 3;                                             \
            const int sc = (s & 7) ^ (row & 7);                                 \
            int gr = brow + row; gr = gr < M ? gr : M - 1;                      \
            gload16(Ab + (size_t)gr * K + (kt) + sc * 8,                        \
                    &As[buf][(g * 256 + wid * 64) * 8]);                        \
        }                                                                       \
    }
#define LOAD_A32(kt)                                                            \
    {                                                                           \
        _Pragma("unroll") for (int g = 0; g < 4; ++g) {                         \
            const int s = g * 256 + tid;                                        \
            const int row = s >> 3;                                             \
            const int sc = (s & 7) ^ (row & 7);                                 \
            int gr = brow + row; gr = gr < M ? gr : M - 1;                      \
            const float* p = Af + (size_t)gr * K + (kt) + sc * 8;               \
            ar[g][0] = *(const float4*)p;                                       \
            ar[g][1] = *(const float4*)(p + 4);                                 \
        }                                                                       \
    }
#define WRITE_A32(buf)                                                          \
    {                                                                           \
        _Pragma("unroll") for (int g = 0; g < 4; ++g) {                         \
            ushort8 u;                                                          \
            u[0] = f2b(ar[g][0].x); u[1] = f2b(ar[g][0].y);                     \
            u[2] = f2b(ar[g][0].z); u[3] = f2b(ar[g][0].w);                     \
            u[4] = f2b(ar[g][1].x); u[5] = f2b(ar[g][1].y);                     \
            u[6] = f2b(ar[g][1].z); u[7] = f2b(ar[g][1].w);                     \
            *(ushort8*)&As[buf][(g * 256 + tid) * 8] = u;                       \
        }                                                                       \
    }

    const int nt = K / 64;

    // ---- prologue: tile 0 -> buf 0 ----
    if (A32) {
        LOAD_A32(0);
        STAGE_B(0, 0);
        WRITE_A32(0);
    } else {
        STAGE_A16(0, 0);
        STAGE_B(0, 0);
    }
    __syncthreads();

    int cur = 0;
    for (int t = 0; t < nt; ++t) {
        const bool more = (t + 1 < nt);
        if (more) {
            if (A32) {
                LOAD_A32((t + 1) * 64);   // issue-early; cvt+write after MFMAs
            } else {
                STAGE_A16(cur ^ 1, (t + 1) * 64);
            }
            STAGE_B(cur ^ 1, (t + 1) * 64);
        }

#pragma unroll
        for (int ks = 0; ks < 2; ++ks) {
            bf16x8 af[4], bf[4];
#pragma unroll
            for (int mi = 0; mi < 4; ++mi) {
                const int row = wr * 64 + mi * 16 + llo;
                af[mi] = *(const bf16x8*)&As[cur][row * 64 + (((ks * 4 + lhi) ^ (llo & 7)) * 8)];
            }
#pragma unroll
            for (int ni = 0; ni < 4; ++ni) {
                const int row = wc * 64 + ni * 16 + llo;
                bf[ni] = *(const bf16x8*)&Bs[cur][row * 64 + (((ks * 4 + lhi) ^ (llo & 7)) * 8)];
            }
#pragma unroll
            for (int mi = 0; mi < 4; ++mi)
#pragma unroll
                for (int ni = 0; ni < 4; ++ni)
                    acc[mi][ni] = __builtin_amdgcn_mfma_f32_16x16x32_bf16(
                        af[mi], bf[ni], acc[mi][ni], 0, 0, 0);
        }

        if (A32 && more) WRITE_A32(cur ^ 1);

        __syncthreads();
        cur ^= 1;
    }

    // ---- epilogue ----
#pragma unroll
    for (int mi = 0; mi < 4; ++mi) {
        const int row0 = brow + wr * 64 + mi * 16 + lhi * 4;
#pragma unroll
        for (int ni = 0; ni < 4; ++ni) {
            const int col = bcol + wc * 64 + ni * 16 + llo;
            const f32x4 v = acc[mi][ni];
#pragma unroll
            for (int r = 0; r < 4; ++r) {
                const int row = row0 + r;
                if (row < M) C[(size_t)row * N + col] = f2b(v[r]);
            }
        }
    }
#undef STAGE_B
#undef STAGE_A16
#undef LOAD_A32
#undef WRITE_A32
}

// ---------------- fused aggregate: self + gather + bias + ELU ----------------

template <int D, bool BF16_OUT>
__global__ __launch_bounds__(256) void k_aggregate(const unsigned short* __restrict__ H,
                                                   const float* __restrict__ bias,
                                                   void* __restrict__ outv,
                                                   const int* __restrict__ row_start,
                                                   const int* __restrict__ csr_src,
                                                   const float* __restrict__ dinv) {
    const int wid = threadIdx.x >> 6;
    const int lane = threadIdx.x & 63;
    int n, c0;
    if (D == 512) { n = blockIdx.x * 4 + wid; c0 = lane * 8; }
    else          { n = blockIdx.x * 8 + wid * 2 + (lane >> 5); c0 = (lane & 31) * 8; }
    if (n >= N_NODES) return;

    const float di = dinv[n];
    float acc[8];
    {
        const float ws = di * di;
        ushort8 v = *(const ushort8*)(H + (size_t)n * D + c0);
#pragma unroll
        for (int e = 0; e < 8; ++e) acc[e] = b2f(v[e]) * ws;
    }

    const int e0 = row_start[n];
    const int e1 = row_start[n + 1];
    int j = e0;
    for (; j + 8 <= e1; j += 8) {
        int s[8];
        float wgt[8];
#pragma unroll
        for (int q = 0; q < 8; ++q) s[q] = csr_src[j + q];
#pragma unroll
        for (int q = 0; q < 8; ++q) wgt[q] = dinv[s[q]] * di;
#pragma unroll
        for (int h = 0; h < 2; ++h) {
            const ushort8 v0 = *(const ushort8*)(H + (size_t)s[h * 4 + 0] * D + c0);
            const ushort8 v1 = *(const ushort8*)(H + (size_t)s[h * 4 + 1] * D + c0);
            const ushort8 v2 = *(const ushort8*)(H + (size_t)s[h * 4 + 2] * D + c0);
            const ushort8 v3 = *(const ushort8*)(H + (size_t)s[h * 4 + 3] * D + c0);
#pragma unroll
            for (int e = 0; e < 8; ++e) {
                acc[e] = fmaf(b2f(v0[e]), wgt[h * 4 + 0], acc[e]);
                acc[e] = fmaf(b2f(v1[e]), wgt[h * 4 + 1], acc[e]);
                acc[e] = fmaf(b2f(v2[e]), wgt[h * 4 + 2], acc[e]);
                acc[e] = fmaf(b2f(v3[e]), wgt[h * 4 + 3], acc[e]);
            }
        }
    }
    for (; j + 4 <= e1; j += 4) {
        const int s0 = csr_src[j + 0];
        const int s1 = csr_src[j + 1];
        const int s2 = csr_src[j + 2];
        const int s3 = csr_src[j + 3];
        const float w0 = dinv[s0] * di;
        const float w1 = dinv[s1] * di;
        const float w2 = dinv[s2] * di;
        const float w3 = dinv[s3] * di;
        const ushort8 v0 = *(const ushort8*)(H + (size_t)s0 * D + c0);
        const ushort8 v1 = *(const ushort8*)(H + (size_t)s1 * D + c0);
        const ushort8 v2 = *(const ushort8*)(H + (size_t)s2 * D + c0);
        const ushort8 v3 = *(const ushort8*)(H + (size_t)s3 * D + c0);
#pragma unroll
        for (int e = 0; e < 8; ++e) {
            acc[e] = fmaf(b2f(v0[e]), w0, acc[e]);
            acc[e] = fmaf(b2f(v1[e]), w1, acc[e]);
            acc[e] = fmaf(b2f(v2[e]), w2, acc[e]);
            acc[e] = fmaf(b2f(v3[e]), w3, acc[e]);
        }
    }
    for (; j < e1; ++j) {
        const int s = csr_src[j];
        const float ws = dinv[s] * di;
        const ushort8 v = *(const ushort8*)(H + (size_t)s * D + c0);
#pragma unroll
        for (int e = 0; e < 8; ++e) acc[e] = fmaf(b2f(v[e]), ws, acc[e]);
    }

#pragma unroll
    for (int e = 0; e < 8; ++e) {
        float t = acc[e] + bias[c0 + e];
        acc[e] = t > 0.f ? t : expf(t) - 1.f;
    }

    if (BF16_OUT) {
        ushort8 o;
#pragma unroll
        for (int e = 0; e < 8; ++e) o[e] = f2b(acc[e]);
        *(ushort8*)((unsigned short*)outv + (size_t)n * D + c0) = o;
    } else {
        float* orow = (float*)outv + (size_t)n * D + c0;
        *(float4*)orow = make_float4(acc[0], acc[1], acc[2], acc[3]);
        *(float4*)(orow + 4) = make_float4(acc[4], acc[5], acc[6], acc[7]);
    }
}

// ---------------- launch ----------------

extern "C" void kernel_launch(void* const* d_in, const int* in_sizes, int n_in,
                              void* d_out, int out_size, void* d_ws, size_t ws_size,
                              hipStream_t stream) {
    const float* x  = (const float*)d_in[0];
    const int* ei   = (const int*)d_in[1];
    const int* src  = ei;
    const int* dst  = ei + N_EDGES;
    const float* W1 = (const float*)d_in[2];
    const float* b1 = (const float*)d_in[3];
    const float* W2 = (const float*)d_in[4];
    const float* b2 = (const float*)d_in[5];
    float* out = (float*)d_out;

    char* ws = (char*)d_ws;
    size_t off = 0;
    auto alloc = [&](size_t bytes) -> void* {
        void* p = ws + off;
        off = (off + bytes + 255) & ~(size_t)255;
        return p;
    };
    int*   indeg     = (int*)alloc((size_t)N_NODES * 4);
    int*   bsum      = (int*)alloc((size_t)NB * 4);
    int*   boff      = (int*)alloc((size_t)NB * 4);
    int*   row_start = (int*)alloc((size_t)(N_NODES + 1) * 4);
    int*   cursor    = (int*)alloc((size_t)N_NODES * 4);
    int*   csr_src   = (int*)alloc((size_t)N_EDGES * 4);
    float* dinv      = (float*)alloc((size_t)N_NODES * 4);
    unsigned short* W1t  = (unsigned short*)alloc((size_t)D_H * D_IN * 2);
    unsigned short* W2t  = (unsigned short*)alloc((size_t)D_OUT * D_H * 2);
    unsigned short* H1   = (unsigned short*)alloc((size_t)N_NODES * D_H * 2);   // 51.2 MB
    unsigned short* out1 = (unsigned short*)alloc((size_t)N_NODES * D_H * 2);   // 51.2 MB
    unsigned short* H2   = (unsigned short*)alloc((size_t)N_NODES * D_OUT * 2); // 25.6 MB

    // CSR build + norms
    k_zero<<<(N_NODES + 255) / 256, 256, 0, stream>>>(indeg, N_NODES);
    k_indeg<<<(N_EDGES + 255) / 256, 256, 0, stream>>>(dst, indeg);
    k_partials<<<NB, 256, 0, stream>>>(indeg, bsum);
    k_scanb<<<1, 256, 0, stream>>>(bsum, boff);
    k_finalize<<<NB, 256, 0, stream>>>(indeg, boff, row_start, cursor, dinv);
    k_bucket<<<(N_EDGES + 255) / 256, 256, 0, stream>>>(src, dst, cursor, csr_src);

    // weight transposes
    {
        dim3 b(32, 8);
        dim3 g1(D_IN / 32, D_H / 32);
        k_wt<<<g1, b, 0, stream>>>(W1, W1t, D_IN, D_H);
        dim3 g2(D_H / 32, D_OUT / 32);
        k_wt<<<g2, b, 0, stream>>>(W2, W2t, D_H, D_OUT);
    }

    const int nrb = (N_NODES + 127) / 128;  // 391

    // ----- layer 1 -----
    {
        dim3 g(D_H / 128, nrb);  // (4, 391)
        k_gemm<true><<<g, 256, 0, stream>>>(x, W1t, H1, N_NODES, D_H, D_IN);
    }
    k_aggregate<512, true><<<(N_NODES + 3) / 4, 256, 0, stream>>>(H1, b1, out1, row_start, csr_src, dinv);

    // ----- layer 2 -----
    {
        dim3 g(D_OUT / 128, nrb);  // (2, 391)
        k_gemm<false><<<g, 256, 0, stream>>>(out1, W2t, H2, N_NODES, D_OUT, D_H);
    }
    k_aggregate<256, false><<<(N_NODES + 7) / 8, 256, 0, stream>>>(H2, b2, out, row_start, csr_src, dinv);
}

// Round 9
// 294.766 us; speedup vs baseline: 1.0692x; 1.0692x over previous
//
#include <hip/hip_runtime.h>
#include <math.h>

#define N_NODES 50000
#define N_EDGES 500000
#define D_IN 512
#define D_H  512
#define D_OUT 256
#define NB 196  // ceil(N_NODES/256)

typedef __attribute__((ext_vector_type(8))) short bf16x8;
typedef __attribute__((ext_vector_type(8))) unsigned short ushort8;
typedef __attribute__((ext_vector_type(4))) float f32x4;

__device__ __forceinline__ float b2f(unsigned short u) {
    union { unsigned int i; float f; } v; v.i = ((unsigned int)u) << 16; return v.f;
}
__device__ __forceinline__ unsigned short f2b(float f) {
    unsigned int x = __float_as_uint(f);
    unsigned int r = (x + 0x7fffu + ((x >> 16) & 1u)) >> 16;  // RNE
    return (unsigned short)r;
}

// ---------------- x fp32 -> bf16 ----------------

__global__ __launch_bounds__(256) void k_cvt(const float* __restrict__ in,
                                             unsigned short* __restrict__ out,
                                             long long n8) {
    long long i = (long long)blockIdx.x * 256 + threadIdx.x;
    if (i >= n8) return;
    float4 v0 = ((const float4*)in)[i * 2];
    float4 v1 = ((const float4*)in)[i * 2 + 1];
    ushort8 o;
    o[0] = f2b(v0.x); o[1] = f2b(v0.y); o[2] = f2b(v0.z); o[3] = f2b(v0.w);
    o[4] = f2b(v1.x); o[5] = f2b(v1.y); o[6] = f2b(v1.z); o[7] = f2b(v1.w);
    ((ushort8*)out)[i] = o;
}

// ---------------- weight transpose: W [K][N] fp32 -> Wt [N][K] bf16 ----------------

__global__ void k_wt(const float* __restrict__ W, unsigned short* __restrict__ Wt,
                     int K, int N) {
    __shared__ float t[32][33];
    const int bk = blockIdx.x * 32, bn = blockIdx.y * 32;
    const int tx = threadIdx.x, ty = threadIdx.y;  // (32,8)
    for (int i = ty; i < 32; i += 8) t[i][tx] = W[(size_t)(bk + i) * N + bn + tx];
    __syncthreads();
    for (int i = ty; i < 32; i += 8)
        Wt[(size_t)(bn + i) * K + bk + tx] = f2b(t[tx][i]);
}

// ---------------- degree / CSR build ----------------

__global__ __launch_bounds__(256) void k_zero(int* __restrict__ p, int n) {
    int i = blockIdx.x * 256 + threadIdx.x;
    if (i < n) p[i] = 0;
}

__global__ __launch_bounds__(256) void k_indeg(const int* __restrict__ dst,
                                               int* __restrict__ indeg) {
    int i = blockIdx.x * 256 + threadIdx.x;
    if (i < N_EDGES) atomicAdd(&indeg[dst[i]], 1);
}

__global__ __launch_bounds__(256) void k_partials(const int* __restrict__ indeg,
                                                  int* __restrict__ bsum) {
    __shared__ int wsum[4];
    const int tid = threadIdx.x, lane = tid & 63, w = tid >> 6;
    const int i = blockIdx.x * 256 + tid;
    int v = (i < N_NODES) ? indeg[i] : 0;
#pragma unroll
    for (int o = 32; o > 0; o >>= 1) v += __shfl_down(v, o, 64);
    if (lane == 0) wsum[w] = v;
    __syncthreads();
    if (tid == 0) bsum[blockIdx.x] = wsum[0] + wsum[1] + wsum[2] + wsum[3];
}

__global__ __launch_bounds__(256) void k_scanb(const int* __restrict__ bsum,
                                               int* __restrict__ boff) {
    __shared__ int wsum[4];
    const int tid = threadIdx.x, lane = tid & 63, w = tid >> 6;
    const int v = (tid < NB) ? bsum[tid] : 0;
    int s = v;
#pragma unroll
    for (int o = 1; o < 64; o <<= 1) {
        int t = __shfl_up(s, o, 64);
        if (lane >= o) s += t;
    }
    if (lane == 63) wsum[w] = s;
    __syncthreads();
    int add = 0;
    for (int k = 0; k < w; ++k) add += wsum[k];
    if (tid < NB) boff[tid] = add + s - v;
}

__global__ __launch_bounds__(256) void k_finalize(const int* __restrict__ indeg,
                                                  const int* __restrict__ boff,
                                                  int* __restrict__ row_start,
                                                  int* __restrict__ cursor,
                                                  float* __restrict__ dinv) {
    __shared__ int wsum[4];
    const int tid = threadIdx.x, lane = tid & 63, w = tid >> 6;
    const int i = blockIdx.x * 256 + tid;
    const int v = (i < N_NODES) ? indeg[i] : 0;
    int s = v;
#pragma unroll
    for (int o = 1; o < 64; o <<= 1) {
        int t = __shfl_up(s, o, 64);
        if (lane >= o) s += t;
    }
    if (lane == 63) wsum[w] = s;
    __syncthreads();
    int add = boff[blockIdx.x];
    for (int k = 0; k < w; ++k) add += wsum[k];
    if (i < N_NODES) {
        const int excl = add + s - v;
        row_start[i] = excl;
        cursor[i] = excl;
        dinv[i] = rsqrtf((float)(1 + v));
    }
    if (i == N_NODES) row_start[N_NODES] = N_EDGES;
}

__global__ __launch_bounds__(256) void k_bucket(const int* __restrict__ src,
                                                const int* __restrict__ dst,
                                                int* __restrict__ cursor,
                                                int* __restrict__ csr_src) {
    int e = blockIdx.x * 256 + threadIdx.x;
    if (e >= N_EDGES) return;
    int pos = atomicAdd(&cursor[dst[e]], 1);
    csr_src[pos] = src[e];
}

// ---------------- 128x128 bf16 GEMM, BK=64, dbuf, swizzled LDS, vec epilogue ----
// C[M,N] = A[M,K] @ Bt[N,K]^T, fp32 accum -> bf16 C.
// 256 threads = 4 waves 2x2; per-wave 64x64 (4x4 frags of 16x16x32, 2 k-halves).
// LDS per operand: [128 rows][8 chunks of 8 bf16], chunk at (c ^ (row&7))
// (involution pre-applied on gload SOURCE; R8-verified, 0 bank conflicts).
// Epilogue: acc -> per-wave 64x64 swizzled LDS tile (b16 DS writes) -> b128
// reads -> dwordx4 C stores (8 per thread vs 64 scalar 2B: VMEM-instr cut).
// Grid: flat with bijective XCD map — all col-blocks of a row-panel on one XCD.

__device__ __forceinline__ void gload16(const void* g, void* l) {
    __builtin_amdgcn_global_load_lds(
        (const __attribute__((address_space(1))) unsigned int*)g,
        (__attribute__((address_space(3))) unsigned int*)l, 16, 0, 0);
}

__global__ __launch_bounds__(256, 2) void k_gemm(const unsigned short* __restrict__ A,
                                                 const unsigned short* __restrict__ Bt,
                                                 unsigned short* __restrict__ C,
                                                 int M, int N, int K,
                                                 int ncb, int nrb) {
    __shared__ __align__(16) short As[2][128 * 64];  // 16 KB x2
    __shared__ __align__(16) short Bs[2][128 * 64];  // 16 KB x2

    const int bid = blockIdx.x;
    const int xcd = bid & 7;
    const int sidx = bid >> 3;
    const int cb = sidx % ncb;
    const int rb = (sidx / ncb) * 8 + xcd;
    if (rb >= nrb) return;
    const int brow = rb * 128;
    const int bcol = cb * 128;

    const int tid = threadIdx.x;
    const int wid = tid >> 6;
    const int lane = tid & 63;
    const int wr = wid >> 1, wc = wid & 1;
    const int lhi = lane >> 4, llo = lane & 15;

    f32x4 acc[4][4];
#pragma unroll
    for (int i = 0; i < 4; ++i)
#pragma unroll
        for (int j = 0; j < 4; ++j) acc[i][j] = (f32x4){0.f, 0.f, 0.f, 0.f};

    // staging: slot s = g*256 + tid; row = s>>3; pos = s&7; src chunk = pos^(row&7)
#define STAGE(buf, kt)                                                          \
    {                                                                           \
        _Pragma("unroll") for (int g = 0; g < 4; ++g) {                         \
            const int s = g * 256 + tid;                                        \
            const int row = s >> 3;                                             \
            const int sc = (s & 7) ^ (row & 7);                                 \
            int gr = brow + row; gr = gr < M ? gr : M - 1;                      \
            gload16(A + (size_t)gr * K + (kt) + sc * 8,                         \
                    &As[buf][(g * 256 + wid * 64) * 8]);                        \
            gload16(Bt + (size_t)(bcol + row) * K + (kt) + sc * 8,              \
                    &Bs[buf][(g * 256 + wid * 64) * 8]);                        \
        }                                                                       \
    }

    const int nt = K / 64;

    STAGE(0, 0);
    __syncthreads();

    int cur = 0;
    for (int t = 0; t < nt; ++t) {
        if (t + 1 < nt) STAGE(cur ^ 1, (t + 1) * 64);

#pragma unroll
        for (int ks = 0; ks < 2; ++ks) {
            bf16x8 af[4], bf[4];
#pragma unroll
            for (int mi = 0; mi < 4; ++mi) {
                const int row = wr * 64 + mi * 16 + llo;
                af[mi] = *(const bf16x8*)&As[cur][row * 64 + (((ks * 4 + lhi) ^ (llo & 7)) * 8)];
            }
#pragma unroll
            for (int ni = 0; ni < 4; ++ni) {
                const int row = wc * 64 + ni * 16 + llo;
                bf[ni] = *(const bf16x8*)&Bs[cur][row * 64 + (((ks * 4 + lhi) ^ (llo & 7)) * 8)];
            }
#pragma unroll
            for (int mi = 0; mi < 4; ++mi)
#pragma unroll
                for (int ni = 0; ni < 4; ++ni)
                    acc[mi][ni] = __builtin_amdgcn_mfma_f32_16x16x32_bf16(
                        af[mi], bf[ni], acc[mi][ni], 0, 0, 0);
        }

        __syncthreads();
        cur ^= 1;
    }
#undef STAGE

    // ---- epilogue: per-wave 64x64 bf16 tile in LDS (swizzled), vec stores ----
    // As = 32 KB total = 4 waves x 4096 shorts. Loop barrier already drained
    // all LDS reads, so As is reusable here.
    short* cws = &As[0][0] + wid * 4096;  // [64 rows][8 chunks of 8], chunk^=(row&7)

#pragma unroll
    for (int mi = 0; mi < 4; ++mi)
#pragma unroll
        for (int ni = 0; ni < 4; ++ni) {
            const f32x4 v = acc[mi][ni];
#pragma unroll
            for (int r = 0; r < 4; ++r) {
                const int row = mi * 16 + lhi * 4 + r;
                const int col = ni * 16 + llo;
                const int chunk = (col >> 3) ^ (row & 7);
                cws[row * 64 + chunk * 8 + (col & 7)] = (short)f2b(v[r]);
            }
        }
    __syncthreads();  // cross-lane transpose: writes visible to reads

    {
        const int rsub = lane >> 3;      // 0..7
        const int c = lane & 7;          // chunk 0..7
#pragma unroll
        for (int i = 0; i < 8; ++i) {
            const int row = i * 8 + rsub;
            const ushort8 o = *(const ushort8*)&cws[row * 64 + ((c ^ (row & 7)) * 8)];
            const int grow = brow + wr * 64 + row;
            if (grow < M)
                *(ushort8*)(C + (size_t)grow * N + bcol + wc * 64 + c * 8) = o;
        }
    }
}

// ---------------- fused aggregate: self + gather + bias + ELU ----------------

template <int D, bool BF16_OUT>
__global__ __launch_bounds__(256) void k_aggregate(const unsigned short* __restrict__ H,
                                                   const float* __restrict__ bias,
                                                   void* __restrict__ outv,
                                                   const int* __restrict__ row_start,
                                                   const int* __restrict__ csr_src,
                                                   const float* __restrict__ dinv) {
    const int wid = threadIdx.x >> 6;
    const int lane = threadIdx.x & 63;
    int n, c0;
    if (D == 512) { n = blockIdx.x * 4 + wid; c0 = lane * 8; }
    else          { n = blockIdx.x * 8 + wid * 2 + (lane >> 5); c0 = (lane & 31) * 8; }
    if (n >= N_NODES) return;

    const float di = dinv[n];
    float acc[8];
    {
        const float ws = di * di;
        ushort8 v = *(const ushort8*)(H + (size_t)n * D + c0);
#pragma unroll
        for (int e = 0; e < 8; ++e) acc[e] = b2f(v[e]) * ws;
    }

    const int e0 = row_start[n];
    const int e1 = row_start[n + 1];
    int j = e0;
    for (; j + 8 <= e1; j += 8) {
        int s[8];
        float wgt[8];
#pragma unroll
        for (int q = 0; q < 8; ++q) s[q] = csr_src[j + q];
#pragma unroll
        for (int q = 0; q < 8; ++q) wgt[q] = dinv[s[q]] * di;
#pragma unroll
        for (int h = 0; h < 2; ++h) {
            const ushort8 v0 = *(const ushort8*)(H + (size_t)s[h * 4 + 0] * D + c0);
            const ushort8 v1 = *(const ushort8*)(H + (size_t)s[h * 4 + 1] * D + c0);
            const ushort8 v2 = *(const ushort8*)(H + (size_t)s[h * 4 + 2] * D + c0);
            const ushort8 v3 = *(const ushort8*)(H + (size_t)s[h * 4 + 3] * D + c0);
#pragma unroll
            for (int e = 0; e < 8; ++e) {
                acc[e] = fmaf(b2f(v0[e]), wgt[h * 4 + 0], acc[e]);
                acc[e] = fmaf(b2f(v1[e]), wgt[h * 4 + 1], acc[e]);
                acc[e] = fmaf(b2f(v2[e]), wgt[h * 4 + 2], acc[e]);
                acc[e] = fmaf(b2f(v3[e]), wgt[h * 4 + 3], acc[e]);
            }
        }
    }
    for (; j + 4 <= e1; j += 4) {
        const int s0 = csr_src[j + 0];
        const int s1 = csr_src[j + 1];
        const int s2 = csr_src[j + 2];
        const int s3 = csr_src[j + 3];
        const float w0 = dinv[s0] * di;
        const float w1 = dinv[s1] * di;
        const float w2 = dinv[s2] * di;
        const float w3 = dinv[s3] * di;
        const ushort8 v0 = *(const ushort8*)(H + (size_t)s0 * D + c0);
        const ushort8 v1 = *(const ushort8*)(H + (size_t)s1 * D + c0);
        const ushort8 v2 = *(const ushort8*)(H + (size_t)s2 * D + c0);
        const ushort8 v3 = *(const ushort8*)(H + (size_t)s3 * D + c0);
#pragma unroll
        for (int e = 0; e < 8; ++e) {
            acc[e] = fmaf(b2f(v0[e]), w0, acc[e]);
            acc[e] = fmaf(b2f(v1[e]), w1, acc[e]);
            acc[e] = fmaf(b2f(v2[e]), w2, acc[e]);
            acc[e] = fmaf(b2f(v3[e]), w3, acc[e]);
        }
    }
    for (; j < e1; ++j) {
        const int s = csr_src[j];
        const float ws = dinv[s] * di;
        const ushort8 v = *(const ushort8*)(H + (size_t)s * D + c0);
#pragma unroll
        for (int e = 0; e < 8; ++e) acc[e] = fmaf(b2f(v[e]), ws, acc[e]);
    }

#pragma unroll
    for (int e = 0; e < 8; ++e) {
        float t = acc[e] + bias[c0 + e];
        acc[e] = t > 0.f ? t : expf(t) - 1.f;
    }

    if (BF16_OUT) {
        ushort8 o;
#pragma unroll
        for (int e = 0; e < 8; ++e) o[e] = f2b(acc[e]);
        *(ushort8*)((unsigned short*)outv + (size_t)n * D + c0) = o;
    } else {
        float* orow = (float*)outv + (size_t)n * D + c0;
        *(float4*)orow = make_float4(acc[0], acc[1], acc[2], acc[3]);
        *(float4*)(orow + 4) = make_float4(acc[4], acc[5], acc[6], acc[7]);
    }
}

// ---------------- launch ----------------

extern "C" void kernel_launch(void* const* d_in, const int* in_sizes, int n_in,
                              void* d_out, int out_size, void* d_ws, size_t ws_size,
                              hipStream_t stream) {
    const float* x  = (const float*)d_in[0];
    const int* ei   = (const int*)d_in[1];
    const int* src  = ei;
    const int* dst  = ei + N_EDGES;
    const float* W1 = (const float*)d_in[2];
    const float* b1 = (const float*)d_in[3];
    const float* W2 = (const float*)d_in[4];
    const float* b2 = (const float*)d_in[5];
    float* out = (float*)d_out;

    char* ws = (char*)d_ws;
    size_t off = 0;
    auto alloc = [&](size_t bytes) -> void* {
        void* p = ws + off;
        off = (off + bytes + 255) & ~(size_t)255;
        return p;
    };
    int*   indeg     = (int*)alloc((size_t)N_NODES * 4);
    int*   bsum      = (int*)alloc((size_t)NB * 4);
    int*   boff      = (int*)alloc((size_t)NB * 4);
    int*   row_start = (int*)alloc((size_t)(N_NODES + 1) * 4);
    int*   cursor    = (int*)alloc((size_t)N_NODES * 4);
    int*   csr_src   = (int*)alloc((size_t)N_EDGES * 4);
    float* dinv      = (float*)alloc((size_t)N_NODES * 4);
    unsigned short* W1t  = (unsigned short*)alloc((size_t)D_H * D_IN * 2);
    unsigned short* W2t  = (unsigned short*)alloc((size_t)D_OUT * D_H * 2);
    unsigned short* xb   = (unsigned short*)alloc((size_t)N_NODES * D_IN * 2);  // 51.2 MB
    unsigned short* H1   = (unsigned short*)alloc((size_t)N_NODES * D_H * 2);   // 51.2 MB
    unsigned short* out1 = (unsigned short*)alloc((size_t)N_NODES * D_H * 2);   // 51.2 MB
    unsigned short* H2   = (unsigned short*)alloc((size_t)N_NODES * D_OUT * 2); // 25.6 MB

    // CSR build + norms
    k_zero<<<(N_NODES + 255) / 256, 256, 0, stream>>>(indeg, N_NODES);
    k_indeg<<<(N_EDGES + 255) / 256, 256, 0, stream>>>(dst, indeg);
    k_partials<<<NB, 256, 0, stream>>>(indeg, bsum);
    k_scanb<<<1, 256, 0, stream>>>(bsum, boff);
    k_finalize<<<NB, 256, 0, stream>>>(indeg, boff, row_start, cursor, dinv);
    k_bucket<<<(N_EDGES + 255) / 256, 256, 0, stream>>>(src, dst, cursor, csr_src);

    // input conversion + weight transposes
    {
        const long long n8 = (long long)N_NODES * D_IN / 8;
        k_cvt<<<(int)((n8 + 255) / 256), 256, 0, stream>>>(x, xb, n8);
        dim3 b(32, 8);
        dim3 g1(D_IN / 32, D_H / 32);
        k_wt<<<g1, b, 0, stream>>>(W1, W1t, D_IN, D_H);
        dim3 g2(D_H / 32, D_OUT / 32);
        k_wt<<<g2, b, 0, stream>>>(W2, W2t, D_H, D_OUT);
    }

    const int nrb = (N_NODES + 127) / 128;  // 391
    const int rgrp = (nrb + 7) / 8;         // 49

    // ----- layer 1 -----
    {
        const int ncb = D_H / 128;          // 4
        k_gemm<<<8 * ncb * rgrp, 256, 0, stream>>>(xb, W1t, H1, N_NODES, D_H, D_IN, ncb, nrb);
    }
    k_aggregate<512, true><<<(N_NODES + 3) / 4, 256, 0, stream>>>(H1, b1, out1, row_start, csr_src, dinv);

    // ----- layer 2 -----
    {
        const int ncb = D_OUT / 128;        // 2
        k_gemm<<<8 * ncb * rgrp, 256, 0, stream>>>(out1, W2t, H2, N_NODES, D_OUT, D_H, ncb, nrb);
    }
    k_aggregate<256, false><<<(N_NODES + 7) / 8, 256, 0, stream>>>(H2, b2, out, row_start, csr_src, dinv);
}